// Round 6
// baseline (184.735 us; speedup 1.0000x reference)
//
#include <hip/hip_runtime.h>
#include <stdint.h>

#define N_B 8
#define A_N 131072
#define T_N 64
#define NUM_TRAIN 256
#define NEG_TAU 0.05f
#define ITEM_CAP 512
#define HSET 512
#define APT 2
#define SEG_A 512                  // anchors per block
#define GBLK_A 256                 // blocks per batch
#define CAPP 128                   // per-segment candidate cap; <<7 stride
// k_C geometry
#define BLK_C 128
#define SEG_C 1024

typedef unsigned long long u64;
typedef unsigned int u32;

// Agent-scope (device) coherent accessors: cross-XCD safe WITHOUT fences (R3 errata: fences =
// L2 writeback storm). Proven correct in R5 (absmax 0).
__device__ __forceinline__ u64 aload64(const u64* p) {
    return __hip_atomic_load((u64*)p, __ATOMIC_RELAXED, __HIP_MEMORY_SCOPE_AGENT);
}
__device__ __forceinline__ int aload32(const int* p) {
    return __hip_atomic_load((int*)p, __ATOMIC_RELAXED, __HIP_MEMORY_SCOPE_AGENT);
}
__device__ __forceinline__ void astore64(u64* p, u64 v) {
    __hip_atomic_store(p, v, __ATOMIC_RELAXED, __HIP_MEMORY_SCOPE_AGENT);
}
__device__ __forceinline__ void astore32(int* p, int v) {
    __hip_atomic_store(p, v, __ATOMIC_RELAXED, __HIP_MEMORY_SCOPE_AGENT);
}

// IoU exactly matching the reference op sequence (no FMA contraction).
__device__ __forceinline__ float iou_one(float ay1, float ax1, float ay2, float ax2,
                                         float a_area, float gy1, float gx1, float gy2,
                                         float gx2, float g_area) {
#pragma clang fp contract(off)
    float ih = fmaxf(fminf(ay2, gy2) - fmaxf(ay1, gy1), 0.0f);
    float iw = fmaxf(fminf(ax2, gx2) - fmaxf(ax1, gx1), 0.0f);
    float inter = ih * iw;
    float uni = (a_area + g_area) - inter;
    return uni > 0.0f ? inter / uni : 0.0f;
}

__device__ __forceinline__ bool in_hset(const int* hset, int a) {
    u32 h = ((u32)a * 2654435761u) >> 23 & (HSET - 1);
    while (true) {
        int v = hset[h];
        if (v == -1) return false;
        if (v == a) return true;
        h = (h + 1) & (HSET - 1);
    }
}

// ============ exact k-th smallest from a PREBUILT 256-bin LDS histogram (256 threads) ========
// Boundary bucket re-scan only; 1 thread/segment, 4 independent agent-loads in flight.
// misc[3] receives total BEFORE any early return. (Proven in R5.)
__device__ u64 tail_select(const u64* list, const int* cnts,
                           const u64* extras, int ecnt, const int* hset, bool use_excl,
                           int k, float scale, u64 ovf_all,
                           int* hist, u64* items, int* misc, int* wsum, u64* result) {
    int tid = threadIdx.x, lane = tid & 63, wid = tid >> 6;
    if (tid == 0) { misc[0] = 0; *result = ovf_all; }
    __syncthreads();

    int h = hist[tid], v = h;
#pragma unroll
    for (int d = 1; d < 64; d <<= 1) {
        int t = __shfl_up(v, d, 64);
        if (lane >= d) v += t;
    }
    if (lane == 63) wsum[wid] = v;
    __syncthreads();
    int total = wsum[0] + wsum[1] + wsum[2] + wsum[3];
    int base = 0;
    for (int w = 0; w < wid; w++) base += wsum[w];
    int incl = base + v, exc = incl - h;
    if (k >= exc && k < incl) { misc[1] = tid; misc[2] = exc; }
    if (tid == 0) misc[3] = total;
    __syncthreads();
    if (k >= total) return ovf_all;   // keep-all (uniform across block)
    int b = misc[1], before = misc[2];

#define PROC(P) do { u64 p_ = (P); int a_ = (int)(u32)p_;                                   \
        if (!use_excl || !in_hset(hset, a_)) {                                              \
            float v_ = __uint_as_float((u32)(p_ >> 32));                                    \
            int bn_ = (int)(v_ * scale); bn_ = bn_ > 255 ? 255 : bn_;                       \
            if (bn_ == b) { int ix_ = atomicAdd(&misc[0], 1);                               \
                            if (ix_ < ITEM_CAP) items[ix_] = p_; } } } while (0)

    int c = aload32(&cnts[tid]);
    const u64* lp = list + ((size_t)tid << 7);
    for (int ci = 0; ci < c; ci += 4) {
        u64 p0 = aload64(&lp[ci]);
        u64 p1 = (ci + 1 < c) ? aload64(&lp[ci + 1]) : 0;
        u64 p2 = (ci + 2 < c) ? aload64(&lp[ci + 2]) : 0;
        u64 p3 = (ci + 3 < c) ? aload64(&lp[ci + 3]) : 0;
        PROC(p0);
        if (ci + 1 < c) PROC(p1);
        if (ci + 2 < c) PROC(p2);
        if (ci + 3 < c) PROC(p3);
    }
    for (int i = tid; i < ecnt; i += 256) PROC(extras[i]);
#undef PROC
    __syncthreads();
    int m = misc[0]; m = m < ITEM_CAP ? m : ITEM_CAP;
    int target = k - before;
    for (int i = tid; i < m; i += 256) {
        u64 p = items[i];
        int r = 0;
        for (int j = 0; j < m; j++) r += (items[j] < p);
        if (r == target) *result = p;
    }
    __syncthreads();
    u64 res = *result;
    __syncthreads();
    return res;
}

// ============ k_main: proven 65us loop + hist build + LAST-FINISHER select (no spin) =========
// Round-16: R5's fused protocol minus the spin storm. 2047 blocks exit right after the
// done-handoff; only the 256th finisher per batch runs the select and writes cutoffs.
// Outputs move to a tiny second dispatch (cross-dispatch flush gives free visibility).
__global__ void __launch_bounds__(256) k_main(const float4* __restrict__ anchors4,
                                              const float4* __restrict__ gts4,
                                              const float* __restrict__ rpos,
                                              const float* __restrict__ rneg,
                                              unsigned char* __restrict__ preclass,
                                              long long* __restrict__ colpack,
                                              u64* __restrict__ pos_list,
                                              u64* __restrict__ neg_list,
                                              int* __restrict__ bcp, int* __restrict__ bcn,
                                              int* __restrict__ hist_pos,
                                              int* __restrict__ hist_neg,
                                              int* __restrict__ done_cnt,
                                              u64* __restrict__ cutoff) {
    __shared__ float4 gbox[T_N];
    __shared__ float gars[T_N];
    __shared__ u64 cmax[T_N];
    __shared__ int lcnt[2];
    __shared__ signed char c0s[SEG_A];
    // tail-only scratch (cold for 2040 of 2048 blocks)
    __shared__ int hist[256];
    __shared__ u64 items[ITEM_CAP];
    __shared__ int hset[HSET];
    __shared__ u64 extras[T_N];
    __shared__ int wnrs[T_N];
    __shared__ int misc[4];
    __shared__ int wsum[4];
    __shared__ int shr[4];
    __shared__ u64 result;
    __shared__ int slast;

    int n = blockIdx.y, bx = blockIdx.x, tid = threadIdx.x, lane = tid & 63;
    int a0 = bx * SEG_A + tid;
    size_t nA = (size_t)n * A_N;

    if (tid < T_N) {
        float4 gb = gts4[n * T_N + tid];
        gbox[tid] = gb;
        {
#pragma clang fp contract(off)
            gars[tid] = (gb.z - gb.x) * (gb.w - gb.y);
        }
        cmax[tid] = 0;   // any pack (v<<32)|~stuff is > 0
    }
    if (tid < 2) lcnt[tid] = 0;
    __syncthreads();

    // ---------------- main phase: identical math to the verified 65us loop ----------------
    float ay1[APT], ax1[APT], ay2[APT], ax2[APT], aar[APT], vmax[APT];
#pragma unroll
    for (int k = 0; k < APT; k++) {
        float4 ab = anchors4[nA + a0 + k * 256];
        float y1 = ab.x, x1 = ab.y, y2 = ab.z, x2 = ab.w;
        bool inb = (y1 >= 0.f) && (x1 >= 0.f) && (y2 <= 1.f) && (x2 <= 1.f);
        if (!inb) { y1 = x1 = y2 = x2 = 0.f; }
        ay1[k] = y1; ax1[k] = x1; ay2[k] = y2; ax2[k] = x2;
        {
#pragma clang fp contract(off)
            aar[k] = (y2 - y1) * (x2 - x1);
        }
        vmax[k] = 0.f;
    }

#pragma unroll 4
    for (int jj = 0; jj < T_N; jj++) {
        int j = (lane + jj) & (T_N - 1);   // lane-staggered: distinct cmax[j] per lane
        float4 gb = gbox[j];
        float gar = gars[j];
        float vb = iou_one(ay1[0], ax1[0], ay2[0], ax2[0], aar[0], gb.x, gb.y, gb.z, gb.w, gar);
        vmax[0] = fmaxf(vmax[0], vb);
        int kb = 0;
#pragma unroll
        for (int k = 1; k < APT; k++) {
            float v = iou_one(ay1[k], ax1[k], ay2[k], ax2[k], aar[k], gb.x, gb.y, gb.z, gb.w, gar);
            vmax[k] = fmaxf(vmax[k], v);
            if (v > vb) { vb = v; kb = k; }
        }
        u64 pk = ((u64)__float_as_uint(vb) << 32) | (u32)(~(u32)(a0 + (kb << 8)));
        atomicMax(&cmax[j], pk);
    }

    // ---------------- classify + candidate lists (agent-scope stores) ----------------
    size_t segbase = ((size_t)(n * GBLK_A + bx)) << 7;
#pragma unroll
    for (int k = 0; k < APT; k++) {
        int a = a0 + k * 256;
        float vm = vmax[k];
        int c0 = (vm < 0.3f) ? 0 : ((vm >= 0.7f) ? 1 : -1);
        c0s[tid + k * 256] = (signed char)c0;
        preclass[nA + a] = (unsigned char)(signed char)c0;
        if (c0 == 1) {
            float rp = rpos[nA + a];
            int sl = atomicAdd(&lcnt[0], 1);
            if (sl < CAPP) {
                astore64(&pos_list[segbase + sl], ((u64)__float_as_uint(rp) << 32) | (u32)a);
                int bb = (int)(rp * 256.0f); bb = bb > 255 ? 255 : bb;
                atomicAdd(&hist_pos[(n << 8) + bb], 1);
            }
        } else if (c0 == 0) {
            float rn = rneg[nA + a];
            if (rn < NEG_TAU) {
                int sl = atomicAdd(&lcnt[1], 1);
                if (sl < CAPP) {
                    astore64(&neg_list[segbase + sl], ((u64)__float_as_uint(rn) << 32) | (u32)a);
                    int bb = (int)(rn * (256.0f / NEG_TAU)); bb = bb > 255 ? 255 : bb;
                    atomicAdd(&hist_neg[(n << 8) + bb], 1);
                }
            }
        }
    }
    __syncthreads();

    // global colpack: value | ~((a<<2)|enc(c0)). a<<2 dominates so the smallest-anchor
    // tie-break is unchanged; enc carries the winner's preclass for the select tail.
    if (tid < T_N) {
        u64 m = cmax[tid];
        u32 wg = ~(u32)m;                       // global anchor of block-local column winner
        int wl = (int)wg - bx * SEG_A;          // local index in [0, SEG_A)
        u32 enc = (u32)c0s[wl] & 3u;            // 0, 1, 3(=-1)
        u64 pk = (m & 0xFFFFFFFF00000000ull) | (u32)(~((wg << 2) | enc));
        atomicMax(&colpack[(n << 6) + tid], (long long)pk);
    }
    if (tid == 0) {
        astore32(&bcp[n * GBLK_A + bx], lcnt[0] < CAPP ? lcnt[0] : CAPP);
        astore32(&bcn[n * GBLK_A + bx], lcnt[1] < CAPP ? lcnt[1] : CAPP);
    }

    // ---------------- completion handoff: NO fence, just completion-wait ----------------
    asm volatile("s_waitcnt vmcnt(0) lgkmcnt(0)" ::: "memory");
    __syncthreads();
    if (tid == 0) slast = (atomicAdd(&done_cnt[n], 1) == GBLK_A - 1) ? 1 : 0;
    __syncthreads();
    if (!slast) return;   // 2047 blocks exit — nobody waits on the select

    // ============ selection tail (the 256th finisher of this batch) ============
    for (int i = tid; i < HSET; i += 256) hset[i] = -1;
    hist[tid] = aload32(&hist_pos[(n << 8) + tid]);
    __syncthreads();

    int w = 0, pcv = 0;
    bool dup = false;
    if (tid < T_N) {
        u64 m = aload64((const u64*)&colpack[(n << 6) + tid]);
        u32 ie = ~(u32)m;
        w = (int)(ie >> 2);
        pcv = ((ie & 3u) == 3u) ? -1 : (int)(ie & 3u);
        wnrs[tid] = w;
        u32 hh = ((u32)w * 2654435761u) >> 23 & (HSET - 1);
        while (true) {
            int old = atomicCAS(&hset[hh], -1, w);
            if (old == -1 || old == w) break;
            hh = (hh + 1) & (HSET - 1);
        }
    }
    __syncthreads();
    if (tid < T_N) {
        for (int t2 = 0; t2 < tid; t2++) dup |= (wnrs[t2] == w);
        bool val = !dup && (pcv != 1);
        u64 mask = __ballot(val);
        if (val) {
            int ix = (int)__popcll(mask & ((1ull << tid) - 1));
            extras[ix] = ((u64)__float_as_uint(rpos[nA + w]) << 32) | (u32)w;
        }
        if (tid == 0) shr[0] = (int)__popcll(mask);
    }
    __syncthreads();
    int extra_cnt = shr[0];
    for (int i = tid; i < extra_cnt; i += 256) {
        float vv = __uint_as_float((u32)(extras[i] >> 32));
        int bb = (int)(vv * 256.0f); bb = bb > 255 ? 255 : bb;
        atomicAdd(&hist[bb], 1);
    }
    __syncthreads();

    u64 cp = tail_select(pos_list + (((size_t)n * GBLK_A) << 7), bcp + n * GBLK_A,
                         extras, extra_cnt, hset, false,
                         NUM_TRAIN / 2, 256.0f, ~0ull,
                         hist, items, misc, wsum, &result);
    int P = misc[3];

    hist[tid] = aload32(&hist_neg[(n << 8) + tid]);
    __syncthreads();
    if (tid < T_N && !dup && pcv == 0) {   // winner-negs were counted; exclude them
        float r = rneg[nA + w];
        if (r < NEG_TAU) {
            int bb = (int)(r * (256.0f / NEG_TAU)); bb = bb > 255 ? 255 : bb;
            atomicAdd(&hist[bb], -1);
        }
    }
    __syncthreads();
    int n_pos = P < NUM_TRAIN / 2 ? P : NUM_TRAIN / 2;
    u64 cn = tail_select(neg_list + (((size_t)n * GBLK_A) << 7), bcn + n * GBLK_A,
                         nullptr, 0, hset, true,
                         NUM_TRAIN - n_pos, 256.0f / NEG_TAU,
                         ((u64)__float_as_uint(NEG_TAU) << 32),
                         hist, items, misc, wsum, &result);
    if (tid == 0) {   // plain stores: consumed next dispatch (kernel-end flush)
        cutoff[2 * n] = cp;
        cutoff[2 * n + 1] = cn;
    }
}

// ============ k_C: final class + coalesced delta stores (winners from colpack) ===============
__global__ void __launch_bounds__(256) k_C(const float4* __restrict__ anchors4,
                                           const float4* __restrict__ gts4,
                                           const u32* __restrict__ preclass32,
                                           const long long* __restrict__ colpack,
                                           const float4* __restrict__ rpos4,
                                           const float4* __restrict__ rneg4,
                                           const u64* __restrict__ cutoff,
                                           float4* __restrict__ out_classes4,
                                           float4* __restrict__ out_deltas) {
    __shared__ float4 gbox[T_N];
    __shared__ float gars[T_N];
    __shared__ u32 wbm[32];   // 1024-bit winner bitmap for this block's anchors
    __shared__ u32 pbm[32];   // 1024-bit final-positive bitmap
    int n = blockIdx.y, bx = blockIdx.x, tid = threadIdx.x;
    size_t nA = (size_t)n * A_N;
    if (tid < 32) { wbm[tid] = 0; pbm[tid] = 0; }
    __syncthreads();
    if (tid < T_N) {
        float4 gb = gts4[n * T_N + tid];
        gbox[tid] = gb;
        {
#pragma clang fp contract(off)
            gars[tid] = (gb.z - gb.x) * (gb.w - gb.y);
        }
        int w = (int)((~(u32)(u64)colpack[(n << 6) + tid]) >> 2);
        int d = w - bx * SEG_C;
        if ((u32)d < (u32)SEG_C) atomicOr(&wbm[d >> 5], 1u << (d & 31));
    }
    __syncthreads();

    size_t gi4 = nA / 4 + bx * 256 + tid;
    u32 pcw = preclass32[gi4];
    float4 rp = rpos4[gi4];
    float4 rn = rneg4[gi4];
    float rpv[4] = {rp.x, rp.y, rp.z, rp.w};
    float rnv[4] = {rn.x, rn.y, rn.z, rn.w};
    int a0 = (bx * 256 + tid) * 4;
    u64 cp = cutoff[2 * n], cn = cutoff[2 * n + 1];

    u32 marked = (wbm[tid >> 3] >> ((tid & 7) * 4)) & 0xF;

    float fcv[4];
#pragma unroll
    for (int j = 0; j < 4; j++) {
        int c = (int)(signed char)((pcw >> (8 * j)) & 0xFF);
        if ((marked >> j) & 1) c = 1;   // winner overrides 0/-1 (>=0.7 already 1)
        int a = a0 + j;
        int fc = -1;
        if (c == 1) {
            u64 p = ((u64)__float_as_uint(rpv[j]) << 32) | (u32)a;
            fc = (p < cp) ? 1 : -1;
        } else if (c == 0) {
            u64 p = ((u64)__float_as_uint(rnv[j]) << 32) | (u32)a;
            fc = (p < cn) ? 0 : -1;
        }
        fcv[j] = (float)fc;
        if (fc == 1) {
            int s = 4 * tid + j;   // slot within block
            atomicOr(&pbm[s >> 5], 1u << (s & 31));
        }
    }
    out_classes4[gi4] = make_float4(fcv[0], fcv[1], fcv[2], fcv[3]);
    __syncthreads();

    int base = bx * SEG_C;   // block's first anchor
#pragma unroll
    for (int j = 0; j < 4; j++) {
        int s = j * 256 + tid;
        float4 d = make_float4(0.f, 0.f, 0.f, 0.f);
        if ((pbm[s >> 5] >> (s & 31)) & 1) {
            int a = base + s;
            float4 ab = anchors4[nA + a];
            float ay1 = ab.x, ax1 = ab.y, ay2 = ab.z, ax2 = ab.w;
            bool inb = (ay1 >= 0.f) && (ax1 >= 0.f) && (ay2 <= 1.f) && (ax2 <= 1.f);
            if (!inb) { ay1 = ax1 = ay2 = ax2 = 0.f; }
            float a_area;
            {
#pragma clang fp contract(off)
                a_area = (ay2 - ay1) * (ax2 - ax1);
            }
            // exact best_gt: strict > keeps FIRST max index == jnp.argmax semantics
            float vm = 0.f; int jb = 0;
            for (int t = 0; t < T_N; t++) {
                float4 gb = gbox[t];
                float v = iou_one(ay1, ax1, ay2, ax2, a_area, gb.x, gb.y, gb.z, gb.w, gars[t]);
                bool g = v > vm;
                vm = g ? v : vm;
                jb = g ? t : jb;
            }
            float4 gb = gbox[jb];
            float ah = ay2 - ay1, aw = ax2 - ax1;
            float acy = ay1 + 0.5f * ah, acx = ax1 + 0.5f * aw;
            float gh = gb.z - gb.x, gw = gb.w - gb.y;
            float gcy = gb.x + 0.5f * gh, gcx = gb.y + 0.5f * gw;
            float ah_s = ah > 0.f ? ah : 1.f, aw_s = aw > 0.f ? aw : 1.f;
            float gh_s = gh > 0.f ? gh : 1.f, gw_s = gw > 0.f ? gw : 1.f;
            d.x = (gcy - acy) / ah_s;
            d.y = (gcx - acx) / aw_s;
            d.z = logf(gh_s / ah_s);
            d.w = logf(gw_s / aw_s);
        }
        out_deltas[nA + base + s] = d;   // wave-contiguous 1KB per store instruction
    }
}

extern "C" void kernel_launch(void* const* d_in, const int* in_sizes, int n_in,
                              void* d_out, int out_size, void* d_ws, size_t ws_size,
                              hipStream_t stream) {
    const float4* anchors4 = (const float4*)d_in[0];
    const float4* gts4     = (const float4*)d_in[1];
    const float*  rpos     = (const float*)d_in[2];
    const float*  rneg     = (const float*)d_in[3];

    char* p = (char*)d_ws;
    // ---- zeroed region (single memset every launch): hist_pos | hist_neg | done_cnt ----
    int* hist_pos_g = (int*)p; p += N_B * 256 * sizeof(int);                   // 8 KB
    int* hist_neg_g = (int*)p; p += N_B * 256 * sizeof(int);                   // 8 KB
    int* done_cnt   = (int*)p; p += N_B * sizeof(int);                         // 32 B
    // ---- not zeroed (poison/stale-safe by construction) ----
    u64* cutoff   = (u64*)p;  p += 2 * N_B * sizeof(u64);                      // always rewritten
    long long* colpack = (long long*)p; p += N_B * T_N * sizeof(long long);    // 4 KB
    u64* pos_list = (u64*)p;  p += (size_t)N_B * GBLK_A * CAPP * sizeof(u64);  // 2 MB
    u64* neg_list = (u64*)p;  p += (size_t)N_B * GBLK_A * CAPP * sizeof(u64);  // 2 MB
    unsigned char* preclass = (unsigned char*)p; p += (size_t)N_B * A_N;       // 1 MB
    int* bcp  = (int*)p;  p += N_B * GBLK_A * sizeof(int);
    int* bcn  = (int*)p;  p += N_B * GBLK_A * sizeof(int);

    float4* out_classes4 = (float4*)d_out;
    float4* out_deltas   = (float4*)((float*)d_out + (size_t)N_B * A_N);

    hipMemsetAsync(hist_pos_g, 0, (2 * N_B * 256 + N_B) * sizeof(int), stream);

    k_main<<<dim3(GBLK_A, N_B), 256, 0, stream>>>(anchors4, gts4, rpos, rneg, preclass,
                                                  colpack, pos_list, neg_list, bcp, bcn,
                                                  hist_pos_g, hist_neg_g, done_cnt, cutoff);
    k_C<<<dim3(BLK_C, N_B), 256, 0, stream>>>(anchors4, gts4, (const u32*)preclass,
                                              colpack, (const float4*)rpos,
                                              (const float4*)rneg, cutoff,
                                              out_classes4, out_deltas);
}

// Round 7
// 167.271 us; speedup vs baseline: 1.1044x; 1.1044x over previous
//
#include <hip/hip_runtime.h>
#include <stdint.h>

#define N_B 8
#define A_N 131072
#define T_N 64
#define NUM_TRAIN 256
#define NEG_TAU 0.05f
#define ITEM_CAP 256
#define HSET 512
#define APT 2
#define SEG_A 512                  // anchors per block
#define GBLK_A 256                 // blocks per batch
#define BINCAP 128                 // per-bin candidate cap (bin counts stay exact regardless)
// k_C geometry
#define BLK_C 128
#define SEG_C 1024

typedef unsigned long long u64;
typedef unsigned int u32;

// Agent-scope (device) coherent accessors: cross-XCD safe WITHOUT fences (R3 errata: fences =
// L2 writeback storm). Proven correct in R5/R6 (absmax 0).
__device__ __forceinline__ u64 aload64(const u64* p) {
    return __hip_atomic_load((u64*)p, __ATOMIC_RELAXED, __HIP_MEMORY_SCOPE_AGENT);
}
__device__ __forceinline__ int aload32(const int* p) {
    return __hip_atomic_load((int*)p, __ATOMIC_RELAXED, __HIP_MEMORY_SCOPE_AGENT);
}
__device__ __forceinline__ void astore64(u64* p, u64 v) {
    __hip_atomic_store(p, v, __ATOMIC_RELAXED, __HIP_MEMORY_SCOPE_AGENT);
}

// IoU exactly matching the reference op sequence (no FMA contraction).
__device__ __forceinline__ float iou_one(float ay1, float ax1, float ay2, float ax2,
                                         float a_area, float gy1, float gx1, float gy2,
                                         float gx2, float g_area) {
#pragma clang fp contract(off)
    float ih = fmaxf(fminf(ay2, gy2) - fmaxf(ay1, gy1), 0.0f);
    float iw = fmaxf(fminf(ax2, gx2) - fmaxf(ax1, gx1), 0.0f);
    float inter = ih * iw;
    float uni = (a_area + g_area) - inter;
    return uni > 0.0f ? inter / uni : 0.0f;
}

__device__ __forceinline__ bool in_hset(const int* hset, int a) {
    u32 h = ((u32)a * 2654435761u) >> 23 & (HSET - 1);
    while (true) {
        int v = hset[h];
        if (v == -1) return false;
        if (v == a) return true;
        h = (h + 1) & (HSET - 1);
    }
}

// ============ exact k-th smallest from bin-partitioned candidates (256 threads) ==============
// Round-17: candidates are stored BY VALUE-BUCKET in k_main (slot = hist atomicAdd return), so
// the old per-segment boundary scan (35us of serial uncached loads, R6-measured) becomes ONE
// coalesced read of the boundary bin (~25 entries). hist = working counts (incl. extras /
// exclusions); gcnt = raw stored counts (for the read length). misc[3] <- total before any
// early return.
__device__ u64 tail_select(const u64* bybin, const int* gcnt,
                           const u64* extras, int ecnt, const int* hset, bool use_excl,
                           int k, float scale, u64 ovf_all,
                           int* hist, u64* items, int* misc, int* wsum, u64* result) {
    int tid = threadIdx.x, lane = tid & 63, wid = tid >> 6;
    if (tid == 0) { misc[0] = 0; *result = ovf_all; }
    __syncthreads();

    int h = hist[tid], v = h;
#pragma unroll
    for (int d = 1; d < 64; d <<= 1) {
        int t = __shfl_up(v, d, 64);
        if (lane >= d) v += t;
    }
    if (lane == 63) wsum[wid] = v;
    __syncthreads();
    int total = wsum[0] + wsum[1] + wsum[2] + wsum[3];
    int base = 0;
    for (int w = 0; w < wid; w++) base += wsum[w];
    int incl = base + v, exc = incl - h;
    if (k >= exc && k < incl) { misc[1] = tid; misc[2] = exc; }
    if (tid == 0) misc[3] = total;
    __syncthreads();
    if (k >= total) return ovf_all;   // keep-all (uniform across block)
    int b = misc[1], before = misc[2];

    int stored = gcnt[b]; stored = stored > BINCAP ? BINCAP : stored;
    for (int i = tid; i < stored; i += 256) {   // ONE coalesced round trip
        u64 p = aload64(&bybin[(size_t)b * BINCAP + i]);
        int a = (int)(u32)p;
        if (!use_excl || !in_hset(hset, a)) {
            int ix = atomicAdd(&misc[0], 1);
            if (ix < ITEM_CAP) items[ix] = p;
        }
    }
    for (int i = tid; i < ecnt; i += 256) {
        u64 p = extras[i];
        float vv = __uint_as_float((u32)(p >> 32));
        int bn = (int)(vv * scale); bn = bn > 255 ? 255 : bn;
        if (bn == b) { int ix = atomicAdd(&misc[0], 1); if (ix < ITEM_CAP) items[ix] = p; }
    }
    __syncthreads();
    int m = misc[0]; m = m < ITEM_CAP ? m : ITEM_CAP;
    int target = k - before;
    for (int i = tid; i < m; i += 256) {
        u64 p = items[i];
        int r = 0;
        for (int j = 0; j < m; j++) r += (items[j] < p);
        if (r == target) *result = p;
    }
    __syncthreads();
    u64 res = *result;
    __syncthreads();
    return res;
}

// ============ k_main: proven 65us loop + bin-partitioned stores + last-finisher select =======
// Protocol (proven R5/R6): agent-scope atomics only, NO fences; s_waitcnt vmcnt(0) + barrier +
// done_cnt handoff; 2047 blocks exit, last finisher per batch selects and writes cutoffs
// (plain stores, consumed next dispatch).
__global__ void __launch_bounds__(256) k_main(const float4* __restrict__ anchors4,
                                              const float4* __restrict__ gts4,
                                              const float* __restrict__ rpos,
                                              const float* __restrict__ rneg,
                                              unsigned char* __restrict__ preclass,
                                              long long* __restrict__ colpack,
                                              u64* __restrict__ pos_bybin,
                                              u64* __restrict__ neg_bybin,
                                              int* __restrict__ hist_pos,
                                              int* __restrict__ hist_neg,
                                              int* __restrict__ done_cnt,
                                              u64* __restrict__ cutoff) {
    __shared__ float4 gbox[T_N];
    __shared__ float gars[T_N];
    __shared__ u64 cmax[T_N];
    __shared__ signed char c0s[SEG_A];
    // tail-only scratch (cold for 2040 of 2048 blocks)
    __shared__ int hist[256];
    __shared__ int gcnt[256];
    __shared__ u64 items[ITEM_CAP];
    __shared__ int hset[HSET];
    __shared__ u64 extras[T_N];
    __shared__ int wnrs[T_N];
    __shared__ int misc[4];
    __shared__ int wsum[4];
    __shared__ int shr[4];
    __shared__ u64 result;
    __shared__ int slast;

    int n = blockIdx.y, bx = blockIdx.x, tid = threadIdx.x, lane = tid & 63;
    int a0 = bx * SEG_A + tid;
    size_t nA = (size_t)n * A_N;

    if (tid < T_N) {
        float4 gb = gts4[n * T_N + tid];
        gbox[tid] = gb;
        {
#pragma clang fp contract(off)
            gars[tid] = (gb.z - gb.x) * (gb.w - gb.y);
        }
        cmax[tid] = 0;   // any pack (v<<32)|~stuff is > 0
    }
    __syncthreads();

    // ---------------- main phase: identical math to the verified 65us loop ----------------
    float ay1[APT], ax1[APT], ay2[APT], ax2[APT], aar[APT], vmax[APT];
#pragma unroll
    for (int k = 0; k < APT; k++) {
        float4 ab = anchors4[nA + a0 + k * 256];
        float y1 = ab.x, x1 = ab.y, y2 = ab.z, x2 = ab.w;
        bool inb = (y1 >= 0.f) && (x1 >= 0.f) && (y2 <= 1.f) && (x2 <= 1.f);
        if (!inb) { y1 = x1 = y2 = x2 = 0.f; }
        ay1[k] = y1; ax1[k] = x1; ay2[k] = y2; ax2[k] = x2;
        {
#pragma clang fp contract(off)
            aar[k] = (y2 - y1) * (x2 - x1);
        }
        vmax[k] = 0.f;
    }

#pragma unroll 4
    for (int jj = 0; jj < T_N; jj++) {
        int j = (lane + jj) & (T_N - 1);   // lane-staggered: distinct cmax[j] per lane
        float4 gb = gbox[j];
        float gar = gars[j];
        float vb = iou_one(ay1[0], ax1[0], ay2[0], ax2[0], aar[0], gb.x, gb.y, gb.z, gb.w, gar);
        vmax[0] = fmaxf(vmax[0], vb);
        int kb = 0;
#pragma unroll
        for (int k = 1; k < APT; k++) {
            float v = iou_one(ay1[k], ax1[k], ay2[k], ax2[k], aar[k], gb.x, gb.y, gb.z, gb.w, gar);
            vmax[k] = fmaxf(vmax[k], v);
            if (v > vb) { vb = v; kb = k; }
        }
        u64 pk = ((u64)__float_as_uint(vb) << 32) | (u32)(~(u32)(a0 + (kb << 8)));
        atomicMax(&cmax[j], pk);
    }

    // ---------------- classify + bin-partitioned candidate stores ----------------
#pragma unroll
    for (int k = 0; k < APT; k++) {
        int a = a0 + k * 256;
        float vm = vmax[k];
        int c0 = (vm < 0.3f) ? 0 : ((vm >= 0.7f) ? 1 : -1);
        c0s[tid + k * 256] = (signed char)c0;
        preclass[nA + a] = (unsigned char)(signed char)c0;
        if (c0 == 1) {
            float rp = rpos[nA + a];
            int bb = (int)(rp * 256.0f); bb = bb > 255 ? 255 : bb;
            int sl = atomicAdd(&hist_pos[(n << 8) + bb], 1);   // count exact; store capped
            if (sl < BINCAP)
                astore64(&pos_bybin[(size_t)((n << 8) + bb) * BINCAP + sl],
                         ((u64)__float_as_uint(rp) << 32) | (u32)a);
        } else if (c0 == 0) {
            float rn = rneg[nA + a];
            if (rn < NEG_TAU) {
                int bb = (int)(rn * (256.0f / NEG_TAU)); bb = bb > 255 ? 255 : bb;
                int sl = atomicAdd(&hist_neg[(n << 8) + bb], 1);
                if (sl < BINCAP)
                    astore64(&neg_bybin[(size_t)((n << 8) + bb) * BINCAP + sl],
                             ((u64)__float_as_uint(rn) << 32) | (u32)a);
            }
        }
    }
    __syncthreads();

    // global colpack: value | ~((a<<2)|enc(c0)). a<<2 dominates so the smallest-anchor
    // tie-break is unchanged; enc carries the winner's preclass for the select tail.
    if (tid < T_N) {
        u64 m = cmax[tid];
        u32 wg = ~(u32)m;                       // global anchor of block-local column winner
        int wl = (int)wg - bx * SEG_A;          // local index in [0, SEG_A)
        u32 enc = (u32)c0s[wl] & 3u;            // 0, 1, 3(=-1)
        u64 pk = (m & 0xFFFFFFFF00000000ull) | (u32)(~((wg << 2) | enc));
        atomicMax(&colpack[(n << 6) + tid], (long long)pk);
    }

    // ---------------- completion handoff: NO fence, just completion-wait ----------------
    asm volatile("s_waitcnt vmcnt(0) lgkmcnt(0)" ::: "memory");
    __syncthreads();
    if (tid == 0) slast = (atomicAdd(&done_cnt[n], 1) == GBLK_A - 1) ? 1 : 0;
    __syncthreads();
    if (!slast) return;   // 2047 blocks exit — nobody waits on the select

    // ============ selection tail (the 256th finisher of this batch) ============
    for (int i = tid; i < HSET; i += 256) hset[i] = -1;
    {
        int g = aload32(&hist_pos[(n << 8) + tid]);
        gcnt[tid] = g;
        hist[tid] = g;
    }
    __syncthreads();

    int w = 0, pcv = 0;
    bool dup = false;
    if (tid < T_N) {
        u64 m = aload64((const u64*)&colpack[(n << 6) + tid]);
        u32 ie = ~(u32)m;
        w = (int)(ie >> 2);
        pcv = ((ie & 3u) == 3u) ? -1 : (int)(ie & 3u);
        wnrs[tid] = w;
        u32 hh = ((u32)w * 2654435761u) >> 23 & (HSET - 1);
        while (true) {
            int old = atomicCAS(&hset[hh], -1, w);
            if (old == -1 || old == w) break;
            hh = (hh + 1) & (HSET - 1);
        }
    }
    __syncthreads();
    if (tid < T_N) {
        for (int t2 = 0; t2 < tid; t2++) dup |= (wnrs[t2] == w);
        bool val = !dup && (pcv != 1);
        u64 mask = __ballot(val);
        if (val) {
            int ix = (int)__popcll(mask & ((1ull << tid) - 1));
            extras[ix] = ((u64)__float_as_uint(rpos[nA + w]) << 32) | (u32)w;
        }
        if (tid == 0) shr[0] = (int)__popcll(mask);
    }
    __syncthreads();
    int extra_cnt = shr[0];
    for (int i = tid; i < extra_cnt; i += 256) {
        float vv = __uint_as_float((u32)(extras[i] >> 32));
        int bb = (int)(vv * 256.0f); bb = bb > 255 ? 255 : bb;
        atomicAdd(&hist[bb], 1);
    }
    __syncthreads();

    u64 cp = tail_select(pos_bybin + ((size_t)(n << 8)) * BINCAP, gcnt,
                         extras, extra_cnt, hset, false,
                         NUM_TRAIN / 2, 256.0f, ~0ull,
                         hist, items, misc, wsum, &result);
    int P = misc[3];

    {
        int g = aload32(&hist_neg[(n << 8) + tid]);
        gcnt[tid] = g;
        hist[tid] = g;
    }
    __syncthreads();
    if (tid < T_N && !dup && pcv == 0) {   // winner-negs were counted; exclude them
        float r = rneg[nA + w];
        if (r < NEG_TAU) {
            int bb = (int)(r * (256.0f / NEG_TAU)); bb = bb > 255 ? 255 : bb;
            atomicAdd(&hist[bb], -1);
        }
    }
    __syncthreads();
    int n_pos = P < NUM_TRAIN / 2 ? P : NUM_TRAIN / 2;
    u64 cn = tail_select(neg_bybin + ((size_t)(n << 8)) * BINCAP, gcnt,
                         nullptr, 0, hset, true,
                         NUM_TRAIN - n_pos, 256.0f / NEG_TAU,
                         ((u64)__float_as_uint(NEG_TAU) << 32),
                         hist, items, misc, wsum, &result);
    if (tid == 0) {   // plain stores: consumed next dispatch (kernel-end flush)
        cutoff[2 * n] = cp;
        cutoff[2 * n + 1] = cn;
    }
}

// ============ k_C: final class + coalesced delta stores (winners from colpack) ===============
__global__ void __launch_bounds__(256) k_C(const float4* __restrict__ anchors4,
                                           const float4* __restrict__ gts4,
                                           const u32* __restrict__ preclass32,
                                           const long long* __restrict__ colpack,
                                           const float4* __restrict__ rpos4,
                                           const float4* __restrict__ rneg4,
                                           const u64* __restrict__ cutoff,
                                           float4* __restrict__ out_classes4,
                                           float4* __restrict__ out_deltas) {
    __shared__ float4 gbox[T_N];
    __shared__ float gars[T_N];
    __shared__ u32 wbm[32];   // 1024-bit winner bitmap for this block's anchors
    __shared__ u32 pbm[32];   // 1024-bit final-positive bitmap
    int n = blockIdx.y, bx = blockIdx.x, tid = threadIdx.x;
    size_t nA = (size_t)n * A_N;
    if (tid < 32) { wbm[tid] = 0; pbm[tid] = 0; }
    __syncthreads();
    if (tid < T_N) {
        float4 gb = gts4[n * T_N + tid];
        gbox[tid] = gb;
        {
#pragma clang fp contract(off)
            gars[tid] = (gb.z - gb.x) * (gb.w - gb.y);
        }
        int w = (int)((~(u32)(u64)colpack[(n << 6) + tid]) >> 2);
        int d = w - bx * SEG_C;
        if ((u32)d < (u32)SEG_C) atomicOr(&wbm[d >> 5], 1u << (d & 31));
    }
    __syncthreads();

    size_t gi4 = nA / 4 + bx * 256 + tid;
    u32 pcw = preclass32[gi4];
    float4 rp = rpos4[gi4];
    float4 rn = rneg4[gi4];
    float rpv[4] = {rp.x, rp.y, rp.z, rp.w};
    float rnv[4] = {rn.x, rn.y, rn.z, rn.w};
    int a0 = (bx * 256 + tid) * 4;
    u64 cp = cutoff[2 * n], cn = cutoff[2 * n + 1];

    u32 marked = (wbm[tid >> 3] >> ((tid & 7) * 4)) & 0xF;

    float fcv[4];
#pragma unroll
    for (int j = 0; j < 4; j++) {
        int c = (int)(signed char)((pcw >> (8 * j)) & 0xFF);
        if ((marked >> j) & 1) c = 1;   // winner overrides 0/-1 (>=0.7 already 1)
        int a = a0 + j;
        int fc = -1;
        if (c == 1) {
            u64 p = ((u64)__float_as_uint(rpv[j]) << 32) | (u32)a;
            fc = (p < cp) ? 1 : -1;
        } else if (c == 0) {
            u64 p = ((u64)__float_as_uint(rnv[j]) << 32) | (u32)a;
            fc = (p < cn) ? 0 : -1;
        }
        fcv[j] = (float)fc;
        if (fc == 1) {
            int s = 4 * tid + j;   // slot within block
            atomicOr(&pbm[s >> 5], 1u << (s & 31));
        }
    }
    out_classes4[gi4] = make_float4(fcv[0], fcv[1], fcv[2], fcv[3]);
    __syncthreads();

    int base = bx * SEG_C;   // block's first anchor
#pragma unroll
    for (int j = 0; j < 4; j++) {
        int s = j * 256 + tid;
        float4 d = make_float4(0.f, 0.f, 0.f, 0.f);
        if ((pbm[s >> 5] >> (s & 31)) & 1) {
            int a = base + s;
            float4 ab = anchors4[nA + a];
            float ay1 = ab.x, ax1 = ab.y, ay2 = ab.z, ax2 = ab.w;
            bool inb = (ay1 >= 0.f) && (ax1 >= 0.f) && (ay2 <= 1.f) && (ax2 <= 1.f);
            if (!inb) { ay1 = ax1 = ay2 = ax2 = 0.f; }
            float a_area;
            {
#pragma clang fp contract(off)
                a_area = (ay2 - ay1) * (ax2 - ax1);
            }
            // exact best_gt: strict > keeps FIRST max index == jnp.argmax semantics
            float vm = 0.f; int jb = 0;
            for (int t = 0; t < T_N; t++) {
                float4 gb = gbox[t];
                float v = iou_one(ay1, ax1, ay2, ax2, a_area, gb.x, gb.y, gb.z, gb.w, gars[t]);
                bool g = v > vm;
                vm = g ? v : vm;
                jb = g ? t : jb;
            }
            float4 gb = gbox[jb];
            float ah = ay2 - ay1, aw = ax2 - ax1;
            float acy = ay1 + 0.5f * ah, acx = ax1 + 0.5f * aw;
            float gh = gb.z - gb.x, gw = gb.w - gb.y;
            float gcy = gb.x + 0.5f * gh, gcx = gb.y + 0.5f * gw;
            float ah_s = ah > 0.f ? ah : 1.f, aw_s = aw > 0.f ? aw : 1.f;
            float gh_s = gh > 0.f ? gh : 1.f, gw_s = gw > 0.f ? gw : 1.f;
            d.x = (gcy - acy) / ah_s;
            d.y = (gcx - acx) / aw_s;
            d.z = logf(gh_s / ah_s);
            d.w = logf(gw_s / aw_s);
        }
        out_deltas[nA + base + s] = d;   // wave-contiguous 1KB per store instruction
    }
}

extern "C" void kernel_launch(void* const* d_in, const int* in_sizes, int n_in,
                              void* d_out, int out_size, void* d_ws, size_t ws_size,
                              hipStream_t stream) {
    const float4* anchors4 = (const float4*)d_in[0];
    const float4* gts4     = (const float4*)d_in[1];
    const float*  rpos     = (const float*)d_in[2];
    const float*  rneg     = (const float*)d_in[3];

    char* p = (char*)d_ws;
    // ---- zeroed region (single memset every launch): hist_pos | hist_neg | done_cnt ----
    int* hist_pos_g = (int*)p; p += N_B * 256 * sizeof(int);                   // 8 KB
    int* hist_neg_g = (int*)p; p += N_B * 256 * sizeof(int);                   // 8 KB
    int* done_cnt   = (int*)p; p += N_B * sizeof(int);                         // 32 B
    // ---- not zeroed (poison/stale-safe by construction) ----
    u64* cutoff   = (u64*)p;  p += 2 * N_B * sizeof(u64);                      // always rewritten
    long long* colpack = (long long*)p; p += N_B * T_N * sizeof(long long);    // 4 KB
    u64* pos_bybin = (u64*)p; p += (size_t)N_B * 256 * BINCAP * sizeof(u64);   // 2 MB
    u64* neg_bybin = (u64*)p; p += (size_t)N_B * 256 * BINCAP * sizeof(u64);   // 2 MB
    unsigned char* preclass = (unsigned char*)p; p += (size_t)N_B * A_N;       // 1 MB

    float4* out_classes4 = (float4*)d_out;
    float4* out_deltas   = (float4*)((float*)d_out + (size_t)N_B * A_N);

    hipMemsetAsync(hist_pos_g, 0, (2 * N_B * 256 + N_B) * sizeof(int), stream);

    k_main<<<dim3(GBLK_A, N_B), 256, 0, stream>>>(anchors4, gts4, rpos, rneg, preclass,
                                                  colpack, pos_bybin, neg_bybin,
                                                  hist_pos_g, hist_neg_g, done_cnt, cutoff);
    k_C<<<dim3(BLK_C, N_B), 256, 0, stream>>>(anchors4, gts4, (const u32*)preclass,
                                              colpack, (const float4*)rpos,
                                              (const float4*)rneg, cutoff,
                                              out_classes4, out_deltas);
}